// Round 13
// baseline (670.912 us; speedup 1.0000x reference)
//
#include <hip/hip_runtime.h>
#include <hip/hip_bf16.h>
#include <math.h>

#define U_CNT 50000
#define I_CNT 50000
#define N_CNT 100000
#define D 64
#define NNZ_CNT 3200000
#define LAYERS 3
#define BATCH 4096
#define L2_REG_F 1e-5f
#define EPS_F 1e-12f

#define NBUCKET 391     // 256 rows per bucket
#define SC_NBLK 256     // scatter blocks (1 per CU), 1024 threads each
#define SC_CHUNK 12500  // NNZ / SC_NBLK
#define BCNT_N (NBUCKET * SC_NBLK)       // 100,096
#define BCNT_NBLK ((BCNT_N + 255) / 256) // 392

typedef __attribute__((ext_vector_type(8))) short short8;
typedef __attribute__((ext_vector_type(4))) float floatx4;

__device__ __forceinline__ unsigned short f32_to_bf16(float f) {
    unsigned int u = __float_as_uint(f);
    u += 0x7FFFu + ((u >> 16) & 1u);   // round-to-nearest-even
    return (unsigned short)(u >> 16);
}
__device__ __forceinline__ float bf16_to_f32(unsigned short h) {
    return __uint_as_float(((unsigned int)h) << 16);
}
__device__ __forceinline__ float bf16_lo(unsigned int u) {
    return __uint_as_float(u << 16);
}
__device__ __forceinline__ float bf16_hi(unsigned int u) {
    return __uint_as_float(u & 0xFFFF0000u);
}
__device__ __forceinline__ unsigned int pack_bf16(float a, float b) {
    return (unsigned int)f32_to_bf16(a) | ((unsigned int)f32_to_bf16(b) << 16);
}

// ---------------- init: all_e[:,0:64] = concat(ue,ie) fp32; E_bf = bf16 copy
__global__ void init_E(const float* __restrict__ ue, const float* __restrict__ ie,
                       unsigned short* __restrict__ Ebf, float* __restrict__ all_e) {
    int tid = blockIdx.x * blockDim.x + threadIdx.x;
    if (tid >= N_CNT * D) return;
    int row = tid >> 6;
    int d = tid & 63;
    float v = (row < U_CNT) ? ue[tid] : ie[tid - U_CNT * D];
    Ebf[tid] = f32_to_bf16(v);
    all_e[(size_t)row * 256 + d] = v;
}

// ---------------- generic hierarchical exclusive scan (n <= 512*256)
__global__ void scan_p1(const int* __restrict__ in, int* __restrict__ bsums, int n) {
    __shared__ int s[256];
    int t = threadIdx.x;
    int i = blockIdx.x * 256 + t;
    int v = (i < n) ? in[i] : 0;
    s[t] = v;
    __syncthreads();
    for (int off = 128; off >= 1; off >>= 1) {
        if (t < off) s[t] += s[t + off];
        __syncthreads();
    }
    if (t == 0) bsums[blockIdx.x] = s[0];
}

__global__ void scan_p2(int* __restrict__ bsums, int nblk) {
    __shared__ int s[512];
    int t = threadIdx.x;
    int v = (t < nblk) ? bsums[t] : 0;
    s[t] = v;
    __syncthreads();
    for (int off = 1; off < 512; off <<= 1) {
        int x = (t >= off) ? s[t - off] : 0;
        __syncthreads();
        s[t] += x;
        __syncthreads();
    }
    if (t < nblk) bsums[t] = s[t] - v;  // exclusive
}

__global__ void scan_p3(const int* __restrict__ in, const int* __restrict__ bsums,
                        int* __restrict__ out, int n) {
    __shared__ int s[256];
    int t = threadIdx.x;
    int i = blockIdx.x * 256 + t;
    int v = (i < n) ? in[i] : 0;
    s[t] = v;
    __syncthreads();
    for (int off = 1; off < 256; off <<= 1) {
        int x = (t >= off) ? s[t - off] : 0;
        __syncthreads();
        s[t] += x;
        __syncthreads();
    }
    if (i < n) out[i] = s[t] - v + bsums[blockIdx.x];
}

// ---------------- per-block bucket histogram -> bcnt[bucket*SC_NBLK + blk]
__global__ __launch_bounds__(1024) void bucket_hist(const int* __restrict__ rows,
                                                    int* __restrict__ bcnt) {
    __shared__ int h[NBUCKET];
    int blk = blockIdx.x, t = threadIdx.x;
    if (t < NBUCKET) h[t] = 0;
    __syncthreads();
    int s = blk * SC_CHUNK, e = s + SC_CHUNK;
    for (int i = s + t; i < e; i += 1024) atomicAdd(&h[rows[i] >> 8], 1);
    __syncthreads();
    if (t < NBUCKET) bcnt[t * SC_NBLK + blk] = h[t];
}

// ---------------- scatter into per-(bucket,block) EXCLUSIVE regions (LDS cursors)
__global__ __launch_bounds__(1024) void block_scatter(const int* __restrict__ rows,
                                                      const int* __restrict__ cols,
                                                      const float* __restrict__ vals,
                                                      const int* __restrict__ boff,
                                                      float2* __restrict__ bbuf) {
    __shared__ int cur[NBUCKET];
    int blk = blockIdx.x, t = threadIdx.x;
    if (t < NBUCKET) cur[t] = boff[t * SC_NBLK + blk];
    __syncthreads();
    int s = blk * SC_CHUNK, e = s + SC_CHUNK;
    for (int i = s + t; i < e; i += 1024) {
        int r = rows[i];
        int b = r >> 8;
        int p = atomicAdd(&cur[b], 1);
        unsigned int bits = ((unsigned int)(r & 255) << 17) | (unsigned int)cols[i];
        bbuf[p] = make_float2(vals[i], __uint_as_float(bits));
    }
}

// ---------------- per-bucket: LDS rowlocal hist -> LDS scan -> row_ptr -> row-sorted packed
__global__ __launch_bounds__(1024) void csr_finalize(const float2* __restrict__ bbuf,
                                                     const int* __restrict__ boff,
                                                     int* __restrict__ row_ptr,
                                                     float2* __restrict__ packed) {
    __shared__ int h[256];
    __shared__ int cur[256];
    int b = blockIdx.x, t = threadIdx.x;
    int s = boff[b * SC_NBLK];
    int e = (b == NBUCKET - 1) ? NNZ_CNT : boff[(b + 1) * SC_NBLK];
    if (t < 256) h[t] = 0;
    __syncthreads();
    for (int i = s + t; i < e; i += 1024)
        atomicAdd(&h[__float_as_uint(bbuf[i].y) >> 17], 1);
    __syncthreads();
    int v = (t < 256) ? h[t] : 0;
    for (int off = 1; off < 256; off <<= 1) {   // Hillis-Steele inclusive scan (t<256)
        int x = (t >= off && t < 256) ? h[t - off] : 0;
        __syncthreads();
        if (t < 256) h[t] += x;
        __syncthreads();
    }
    if (t < 256) {
        int start = s + h[t] - v;  // exclusive + bucket base
        int row = (b << 8) + t;
        if (row < N_CNT) row_ptr[row] = start;
        cur[t] = start;
        if (b == 0 && t == 0) row_ptr[N_CNT] = NNZ_CNT;
    }
    __syncthreads();
    for (int i = s + t; i < e; i += 1024) {
        float2 rec = bbuf[i];
        unsigned int bits = __float_as_uint(rec.y);
        int p = atomicAdd(&cur[bits >> 17], 1);
        packed[p] = make_float2(rec.x, __int_as_float(bits & 0x1FFFFu));
    }
}

// ---------------- FUSED: per 16-row tile, spmm row-sums (registers) -> A-staging (LDS)
// -> MFMA Y = leaky([Lm+E | Lm*E] @ [W1;W2] + b) -> Eout + normalized all_e.
// PING-PONG E: gathers read Ein only, epilogue writes Eout only -> no cross-wave race.
#define AP 136  // A/B^T row stride in shorts (128 + 8 pad -> 4-bank stagger)
__global__ __launch_bounds__(256) void spmm_layer_mfma(const float2* __restrict__ packed,
                                                       const int* __restrict__ row_ptr,
                                                       const unsigned short* __restrict__ Ein,
                                                       unsigned short* __restrict__ Eout,
                                                       const float* __restrict__ W1,
                                                       const float* __restrict__ b1,
                                                       const float* __restrict__ W2,
                                                       const float* __restrict__ b2,
                                                       float* __restrict__ all_e, int layer) {
    __shared__ unsigned short sBt[64 * AP];    // B^T[n][k] bf16 (k<64: W1, k>=64: W2)
    __shared__ float sBias[64];
    __shared__ unsigned short sA[4][16 * AP];  // per-wave A staging

    int t = threadIdx.x;
    for (int i = t; i < 4096; i += 256) {
        int k = i >> 6, n = i & 63;
        sBt[n * AP + k] = f32_to_bf16(W1[i]);
        sBt[n * AP + 64 + k] = f32_to_bf16(W2[i]);
    }
    if (t < 64) sBias[t] = b1[t] + b2[t];
    __syncthreads();

    int w = t >> 6, lane = t & 63;
    int quad = lane >> 4, l16 = lane & 15;
    int sub = lane >> 2;       // [0,16): spmm subgroup
    int sl = lane & 3;         // [0,4)
    int eidx = sub >> 1;       // edge slot [0,8)
    int half = sub & 1;        // row half
    int dbase = half * 32 + sl * 8;  // this lane's 8 dims

    short8 bfrag[4][4];
#pragma unroll
    for (int ks = 0; ks < 4; ks++)
#pragma unroll
        for (int ct = 0; ct < 4; ct++)
            bfrag[ks][ct] = *(const short8*)&sBt[(ct * 16 + l16) * AP + ks * 32 + quad * 8];

    float bias[4];
#pragma unroll
    for (int ct = 0; ct < 4; ct++) bias[ct] = sBias[ct * 16 + l16];

    unsigned short* A = sA[w];
    int col_off = (layer + 1) * 64;
    int nwaves = gridDim.x * 4;

    for (int tile = blockIdx.x * 4 + w; tile < N_CNT / 16; tile += nwaves) {
        int rbase = tile * 16;
        // ---- spmm phase: 16 row-sums, 8 edges in flight per row (reads Ein only)
        for (int r = 0; r < 16; r++) {
            int row = rbase + r;
            int s = row_ptr[row];
            int e = row_ptr[row + 1];
            float a0 = 0.f, a1 = 0.f, a2 = 0.f, a3 = 0.f;
            float a4 = 0.f, a5 = 0.f, a6 = 0.f, a7 = 0.f;
            int i = s + eidx;
            float2 rec = (i < e) ? packed[i] : make_float2(0.f, __int_as_float(0));
            while (i < e) {
                int inext = i + 8;
                float2 rnext = (inext < e) ? packed[inext] : make_float2(0.f, __int_as_float(0));
                int c = __float_as_int(rec.y);
                uint4 ev = *(const uint4*)(Ein + (size_t)c * D + dbase);
                float v = rec.x;
                a0 += v * bf16_lo(ev.x); a1 += v * bf16_hi(ev.x);
                a2 += v * bf16_lo(ev.y); a3 += v * bf16_hi(ev.y);
                a4 += v * bf16_lo(ev.z); a5 += v * bf16_hi(ev.z);
                a6 += v * bf16_lo(ev.w); a7 += v * bf16_hi(ev.w);
                rec = rnext;
                i = inext;
            }
#pragma unroll
            for (int off = 32; off >= 8; off >>= 1) {
                a0 += __shfl_xor(a0, off, 64); a1 += __shfl_xor(a1, off, 64);
                a2 += __shfl_xor(a2, off, 64); a3 += __shfl_xor(a3, off, 64);
                a4 += __shfl_xor(a4, off, 64); a5 += __shfl_xor(a5, off, 64);
                a6 += __shfl_xor(a6, off, 64); a7 += __shfl_xor(a7, off, 64);
            }
            if (eidx == 0) {  // lanes 0..7 hold dims dbase..dbase+7 of Lm[row]
                uint4 eh = *(const uint4*)(Ein + (size_t)row * D + dbase);
                float e0 = bf16_lo(eh.x), e1 = bf16_hi(eh.x);
                float e2 = bf16_lo(eh.y), e3 = bf16_hi(eh.y);
                float e4 = bf16_lo(eh.z), e5 = bf16_hi(eh.z);
                float e6 = bf16_lo(eh.w), e7 = bf16_hi(eh.w);
                *(uint4*)&A[r * AP + dbase] =
                    make_uint4(pack_bf16(a0 + e0, a1 + e1), pack_bf16(a2 + e2, a3 + e3),
                               pack_bf16(a4 + e4, a5 + e5), pack_bf16(a6 + e6, a7 + e7));
                *(uint4*)&A[r * AP + 64 + dbase] =
                    make_uint4(pack_bf16(a0 * e0, a1 * e1), pack_bf16(a2 * e2, a3 * e3),
                               pack_bf16(a4 * e4, a5 * e5), pack_bf16(a6 * e6, a7 * e7));
            }
        }
        // ---- MFMA phase (wave-private sA; in-wave LDS ordering, no barrier needed)
        floatx4 acc[4];
#pragma unroll
        for (int ct = 0; ct < 4; ct++) {
            acc[ct][0] = bias[ct]; acc[ct][1] = bias[ct];
            acc[ct][2] = bias[ct]; acc[ct][3] = bias[ct];
        }
#pragma unroll
        for (int ks = 0; ks < 4; ks++) {
            short8 af = *(const short8*)&A[l16 * AP + ks * 32 + quad * 8];
#pragma unroll
            for (int ct = 0; ct < 4; ct++)
                acc[ct] = __builtin_amdgcn_mfma_f32_16x16x32_bf16(af, bfrag[ks][ct], acc[ct], 0, 0, 0);
        }
        float y[4][4];
        float ssq[4] = {0.f, 0.f, 0.f, 0.f};
#pragma unroll
        for (int ct = 0; ct < 4; ct++)
#pragma unroll
            for (int reg = 0; reg < 4; reg++) {
                float v = acc[ct][reg];
                v = (v > 0.f) ? v : 0.2f * v;
                y[ct][reg] = v;
                ssq[reg] += v * v;
            }
#pragma unroll
        for (int reg = 0; reg < 4; reg++) {
            float ss = ssq[reg];
            ss += __shfl_xor(ss, 1, 64);
            ss += __shfl_xor(ss, 2, 64);
            ss += __shfl_xor(ss, 4, 64);
            ss += __shfl_xor(ss, 8, 64);
            ssq[reg] = fmaxf(sqrtf(ss), EPS_F);
        }
#pragma unroll
        for (int reg = 0; reg < 4; reg++) {
            int row = rbase + quad * 4 + reg;
            float inv = 1.0f / ssq[reg];
#pragma unroll
            for (int ct = 0; ct < 4; ct++) {
                int col = ct * 16 + l16;
                float v = y[ct][reg];
                Eout[(size_t)row * 64 + col] = f32_to_bf16(v);
                all_e[(size_t)row * 256 + col_off + col] = v * inv;
            }
        }
    }
}

// ---------------- scoring: one wave per sample, per-sample partials (NO atomics)
__device__ __forceinline__ float dot4(float4 a, float4 b) {
    return a.x * b.x + a.y * b.y + a.z * b.z + a.w * b.w;
}

__global__ __launch_bounds__(256) void score_kernel(const float* __restrict__ all_e,
                                                    const int* __restrict__ users,
                                                    const int* __restrict__ pos,
                                                    const int* __restrict__ neg,
                                                    float4* __restrict__ partials) {
    int wid = (blockIdx.x * blockDim.x + threadIdx.x) >> 6;
    int lane = threadIdx.x & 63;
    if (wid >= BATCH) return;
    int ui = users[wid];
    int pi = pos[wid];
    int ni = neg[wid];
    const float4* uv4 = (const float4*)(all_e + (size_t)ui * 256);
    const float4* pv4 = (const float4*)(all_e + (size_t)pi * 256);
    const float4* nv4 = (const float4*)(all_e + (size_t)ni * 256);
    float4 uv = uv4[lane];
    float4 pv = pv4[lane];
    float4 nv = nv4[lane];
    float s_up = dot4(uv, pv);
    float s_un = dot4(uv, nv);
    float s_uu = dot4(uv, uv);
    float s_pp = dot4(pv, pv);
    float s_nn = dot4(nv, nv);
#pragma unroll
    for (int off = 32; off >= 1; off >>= 1) {
        s_up += __shfl_xor(s_up, off, 64);
        s_un += __shfl_xor(s_un, off, 64);
        s_uu += __shfl_xor(s_uu, off, 64);
        s_pp += __shfl_xor(s_pp, off, 64);
        s_nn += __shfl_xor(s_nn, off, 64);
    }
    if (lane == 0) {
        float x = s_up - s_un;
        float ls = fminf(x, 0.f) - log1pf(expf(-fabsf(x)));  // log_sigmoid
        partials[wid] = make_float4(-ls, s_uu, s_pp, s_nn);
    }
}

// single-block tree reduction over 4096 float4 partials + final scalar
__global__ __launch_bounds__(256) void reduce_finalize(const float4* __restrict__ partials,
                                                       float* __restrict__ out) {
    __shared__ float4 s[256];
    int t = threadIdx.x;
    float4 a = make_float4(0.f, 0.f, 0.f, 0.f);
    for (int i = t; i < BATCH; i += 256) {
        float4 p = partials[i];
        a.x += p.x; a.y += p.y; a.z += p.z; a.w += p.w;
    }
    s[t] = a;
    __syncthreads();
    for (int off = 128; off >= 1; off >>= 1) {
        if (t < off) {
            s[t].x += s[t + off].x;
            s[t].y += s[t + off].y;
            s[t].z += s[t + off].z;
            s[t].w += s[t + off].w;
        }
        __syncthreads();
    }
    if (t == 0) {
        float bpr = s[0].x / (float)BATCH;
        float l2norm = (s[0].y + s[0].z + sqrtf(s[0].w)) * 0.5f;
        out[0] = bpr + L2_REG_F * l2norm / (float)BATCH;
    }
}

extern "C" void kernel_launch(void* const* d_in, const int* in_sizes, int n_in,
                              void* d_out, int out_size, void* d_ws, size_t ws_size,
                              hipStream_t stream) {
    const int* users = (const int*)d_in[0];
    const int* pos_items = (const int*)d_in[1];
    const int* neg_items = (const int*)d_in[2];
    const int* rows = (const int*)d_in[3];
    const int* cols = (const int*)d_in[4];
    const float* vals = (const float*)d_in[5];
    const float* user_embed = (const float*)d_in[6];
    const float* item_embed = (const float*)d_in[7];
    const float* W1 = (const float*)d_in[8];
    const float* b1 = (const float*)d_in[9];
    const float* W2 = (const float*)d_in[10];
    const float* b2 = (const float*)d_in[11];
    float* out = (float*)d_out;

    char* ws = (char*)d_ws;
    // workspace layout (ping-pong E, no Lm): total ~154.5 MB (matches r10 passing layout)
    size_t off_alle = 0;                                     // 102,400,000
    size_t off_packed = off_alle + (size_t)N_CNT * 256 * 4;  // 25,600,000
    size_t off_EbfA = off_packed + (size_t)NNZ_CNT * 8;      // 12,800,000
    size_t off_EbfB = off_EbfA + (size_t)N_CNT * D * 2;      // 12,800,000
    size_t off_rowptr = off_EbfB + (size_t)N_CNT * D * 2;    // 400,128
    size_t off_blkB = off_rowptr + 400128;                   // 2,048
    size_t off_bcnt = off_blkB + 2048;                       // 400,384
    size_t off_part = off_bcnt + 400384;                     // 65,536

    float* all_e = (float*)(ws + off_alle);
    float2* bbuf = (float2*)(ws + off_alle);   // aliases all_e; dead before init_E runs
    float2* packed = (float2*)(ws + off_packed);
    unsigned short* EbfA = (unsigned short*)(ws + off_EbfA);
    unsigned short* EbfB = (unsigned short*)(ws + off_EbfB);
    int* row_ptr = (int*)(ws + off_rowptr);
    int* blkB = (int*)(ws + off_blkB);
    int* bcnt = (int*)(ws + off_bcnt);
    float4* partials = (float4*)(ws + off_part);

    // bucketed multisplit with exclusive per-(bucket,block) regions
    bucket_hist<<<SC_NBLK, 1024, 0, stream>>>(rows, bcnt);
    scan_p1<<<BCNT_NBLK, 256, 0, stream>>>(bcnt, blkB, BCNT_N);
    scan_p2<<<1, 512, 0, stream>>>(blkB, BCNT_NBLK);
    scan_p3<<<BCNT_NBLK, 256, 0, stream>>>(bcnt, blkB, bcnt, BCNT_N);  // in-place
    block_scatter<<<SC_NBLK, 1024, 0, stream>>>(rows, cols, vals, bcnt, bbuf);
    csr_finalize<<<NBUCKET, 1024, 0, stream>>>(bbuf, bcnt, row_ptr, packed);

    // embeddings (after csr_finalize: bbuf aliases all_e)
    init_E<<<(N_CNT * D) / 256, 256, 0, stream>>>(user_embed, item_embed, EbfA, all_e);

    for (int l = 0; l < LAYERS; l++) {
        const unsigned short* Ein = (l & 1) ? EbfB : EbfA;
        unsigned short* Eout = (l & 1) ? EbfA : EbfB;
        spmm_layer_mfma<<<1024, 256, 0, stream>>>(packed, row_ptr, Ein, Eout,
                                                  W1 + (size_t)l * 4096, b1 + (size_t)l * 64,
                                                  W2 + (size_t)l * 4096, b2 + (size_t)l * 64,
                                                  all_e, l);
    }

    score_kernel<<<(BATCH * 64) / 256, 256, 0, stream>>>(all_e, users, pos_items, neg_items,
                                                         partials);
    reduce_finalize<<<1, 256, 0, stream>>>(partials, out);
}

// Round 14
// 439.866 us; speedup vs baseline: 1.5253x; 1.5253x over previous
//
#include <hip/hip_runtime.h>
#include <hip/hip_bf16.h>
#include <hip/hip_fp16.h>
#include <math.h>

#define U_CNT 50000
#define I_CNT 50000
#define N_CNT 100000
#define D 64
#define NNZ_CNT 3200000
#define LAYERS 3
#define BATCH 4096
#define L2_REG_F 1e-5f
#define EPS_F 1e-12f

#define NBUCKET 391     // 256 rows per bucket
#define SC_NBLK 256     // scatter blocks (1 per CU), 1024 threads each
#define SC_CHUNK 12500  // NNZ / SC_NBLK
#define BCNT_N (NBUCKET * SC_NBLK)       // 100,096
#define BCNT_NBLK ((BCNT_N + 255) / 256) // 392

typedef __attribute__((ext_vector_type(8))) short short8;
typedef __attribute__((ext_vector_type(4))) float floatx4;

__device__ __forceinline__ unsigned short f32_to_bf16(float f) {
    unsigned int u = __float_as_uint(f);
    u += 0x7FFFu + ((u >> 16) & 1u);   // round-to-nearest-even
    return (unsigned short)(u >> 16);
}
__device__ __forceinline__ float bf16_to_f32(unsigned short h) {
    return __uint_as_float(((unsigned int)h) << 16);
}
__device__ __forceinline__ float bf16_lo(unsigned int u) {
    return __uint_as_float(u << 16);
}
__device__ __forceinline__ float bf16_hi(unsigned int u) {
    return __uint_as_float(u & 0xFFFF0000u);
}
__device__ __forceinline__ unsigned int pack_bf16(float a, float b) {
    return (unsigned int)f32_to_bf16(a) | ((unsigned int)f32_to_bf16(b) << 16);
}
// e5m2 = top byte of fp16 (1s+5e+2m). Decode: byte<<8 -> fp16 -> f32 (HW cvt).
__device__ __forceinline__ float e5_to_f32(unsigned int hbits16) {
    return __half2float(__ushort_as_half((unsigned short)hbits16));
}
__device__ __forceinline__ unsigned char f32_to_e5(float f) {
    unsigned short b = __half_as_ushort(__float2half(f));
    b = (unsigned short)(b + 0x7F + ((b >> 8) & 1));  // RNE at byte boundary
    return (unsigned char)(b >> 8);
}

// ---------------- init: all_e[:,0:64] fp32; Ebf bf16; E5 e5m2
__global__ void init_E(const float* __restrict__ ue, const float* __restrict__ ie,
                       unsigned short* __restrict__ Ebf, unsigned char* __restrict__ E5,
                       float* __restrict__ all_e) {
    int tid = blockIdx.x * blockDim.x + threadIdx.x;
    if (tid >= N_CNT * D) return;
    int row = tid >> 6;
    int d = tid & 63;
    float v = (row < U_CNT) ? ue[tid] : ie[tid - U_CNT * D];
    Ebf[tid] = f32_to_bf16(v);
    E5[tid] = f32_to_e5(v);
    all_e[(size_t)row * 256 + d] = v;
}

// ---------------- generic hierarchical exclusive scan (n <= 512*256)
__global__ void scan_p1(const int* __restrict__ in, int* __restrict__ bsums, int n) {
    __shared__ int s[256];
    int t = threadIdx.x;
    int i = blockIdx.x * 256 + t;
    int v = (i < n) ? in[i] : 0;
    s[t] = v;
    __syncthreads();
    for (int off = 128; off >= 1; off >>= 1) {
        if (t < off) s[t] += s[t + off];
        __syncthreads();
    }
    if (t == 0) bsums[blockIdx.x] = s[0];
}

__global__ void scan_p2(int* __restrict__ bsums, int nblk) {
    __shared__ int s[512];
    int t = threadIdx.x;
    int v = (t < nblk) ? bsums[t] : 0;
    s[t] = v;
    __syncthreads();
    for (int off = 1; off < 512; off <<= 1) {
        int x = (t >= off) ? s[t - off] : 0;
        __syncthreads();
        s[t] += x;
        __syncthreads();
    }
    if (t < nblk) bsums[t] = s[t] - v;  // exclusive
}

__global__ void scan_p3(const int* __restrict__ in, const int* __restrict__ bsums,
                        int* __restrict__ out, int n) {
    __shared__ int s[256];
    int t = threadIdx.x;
    int i = blockIdx.x * 256 + t;
    int v = (i < n) ? in[i] : 0;
    s[t] = v;
    __syncthreads();
    for (int off = 1; off < 256; off <<= 1) {
        int x = (t >= off) ? s[t - off] : 0;
        __syncthreads();
        s[t] += x;
        __syncthreads();
    }
    if (i < n) out[i] = s[t] - v + bsums[blockIdx.x];
}

// ---------------- per-block bucket histogram -> bcnt[bucket*SC_NBLK + blk]
__global__ __launch_bounds__(1024) void bucket_hist(const int* __restrict__ rows,
                                                    int* __restrict__ bcnt) {
    __shared__ int h[NBUCKET];
    int blk = blockIdx.x, t = threadIdx.x;
    if (t < NBUCKET) h[t] = 0;
    __syncthreads();
    int s = blk * SC_CHUNK, e = s + SC_CHUNK;
    for (int i = s + t; i < e; i += 1024) atomicAdd(&h[rows[i] >> 8], 1);
    __syncthreads();
    if (t < NBUCKET) bcnt[t * SC_NBLK + blk] = h[t];
}

// ---------------- scatter into per-(bucket,block) EXCLUSIVE regions (LDS cursors)
__global__ __launch_bounds__(1024) void block_scatter(const int* __restrict__ rows,
                                                      const int* __restrict__ cols,
                                                      const float* __restrict__ vals,
                                                      const int* __restrict__ boff,
                                                      float2* __restrict__ bbuf) {
    __shared__ int cur[NBUCKET];
    int blk = blockIdx.x, t = threadIdx.x;
    if (t < NBUCKET) cur[t] = boff[t * SC_NBLK + blk];
    __syncthreads();
    int s = blk * SC_CHUNK, e = s + SC_CHUNK;
    for (int i = s + t; i < e; i += 1024) {
        int r = rows[i];
        int b = r >> 8;
        int p = atomicAdd(&cur[b], 1);
        unsigned int bits = ((unsigned int)(r & 255) << 17) | (unsigned int)cols[i];
        bbuf[p] = make_float2(vals[i], __uint_as_float(bits));
    }
}

// ---------------- per-bucket: LDS rowlocal hist -> LDS scan -> row_ptr -> row-sorted packed
__global__ __launch_bounds__(1024) void csr_finalize(const float2* __restrict__ bbuf,
                                                     const int* __restrict__ boff,
                                                     int* __restrict__ row_ptr,
                                                     float2* __restrict__ packed) {
    __shared__ int h[256];
    __shared__ int cur[256];
    int b = blockIdx.x, t = threadIdx.x;
    int s = boff[b * SC_NBLK];
    int e = (b == NBUCKET - 1) ? NNZ_CNT : boff[(b + 1) * SC_NBLK];
    if (t < 256) h[t] = 0;
    __syncthreads();
    for (int i = s + t; i < e; i += 1024)
        atomicAdd(&h[__float_as_uint(bbuf[i].y) >> 17], 1);
    __syncthreads();
    int v = (t < 256) ? h[t] : 0;
    for (int off = 1; off < 256; off <<= 1) {   // Hillis-Steele inclusive scan (t<256)
        int x = (t >= off && t < 256) ? h[t - off] : 0;
        __syncthreads();
        if (t < 256) h[t] += x;
        __syncthreads();
    }
    if (t < 256) {
        int start = s + h[t] - v;  // exclusive + bucket base
        int row = (b << 8) + t;
        if (row < N_CNT) row_ptr[row] = start;
        cur[t] = start;
        if (b == 0 && t == 0) row_ptr[N_CNT] = NNZ_CNT;
    }
    __syncthreads();
    for (int i = s + t; i < e; i += 1024) {
        float2 rec = bbuf[i];
        unsigned int bits = __float_as_uint(rec.y);
        int p = atomicAdd(&cur[bits >> 17], 1);
        packed[p] = make_float2(rec.x, __int_as_float(bits & 0x1FFFFu));
    }
}

// ---------------- SpMM: one wave per row; 8 subgroups x 8 lanes; e5m2 E rows (64 B =
// ONE cache line per edge). Lane loads 8 B (8 dims), decode = shift + v_cvt_f32_f16.
__global__ __launch_bounds__(256) void spmm_e5(const float2* __restrict__ packed,
                                               const int* __restrict__ row_ptr,
                                               const unsigned char* __restrict__ E5,
                                               unsigned short* __restrict__ Lm) {
    int wid = (blockIdx.x * blockDim.x + threadIdx.x) >> 6;
    int lane = threadIdx.x & 63;
    if (wid >= N_CNT) return;
    int s = row_ptr[wid];
    int e = row_ptr[wid + 1];
    int sub = lane >> 3;   // edge slot [0,8)
    int sl = lane & 7;     // dims 8*sl .. 8*sl+7
    float a0 = 0.f, a1 = 0.f, a2 = 0.f, a3 = 0.f;
    float a4 = 0.f, a5 = 0.f, a6 = 0.f, a7 = 0.f;
    int i = s + sub;
    float2 rec = (i < e) ? packed[i] : make_float2(0.f, __int_as_float(0));
    while (i < e) {
        int inext = i + 8;
        float2 rnext = (inext < e) ? packed[inext] : make_float2(0.f, __int_as_float(0));
        int c = __float_as_int(rec.y);
        uint2 ev = *(const uint2*)(E5 + (size_t)c * D + 8 * sl);
        float v = rec.x;
        unsigned int u = ev.x;
        a0 += v * e5_to_f32((u << 8) & 0xFF00u);
        a1 += v * e5_to_f32(u & 0xFF00u);
        a2 += v * e5_to_f32((u >> 8) & 0xFF00u);
        a3 += v * e5_to_f32((u >> 16) & 0xFF00u);
        u = ev.y;
        a4 += v * e5_to_f32((u << 8) & 0xFF00u);
        a5 += v * e5_to_f32(u & 0xFF00u);
        a6 += v * e5_to_f32((u >> 8) & 0xFF00u);
        a7 += v * e5_to_f32((u >> 16) & 0xFF00u);
        rec = rnext;
        i = inext;
    }
#pragma unroll
    for (int off = 32; off >= 8; off >>= 1) {
        a0 += __shfl_xor(a0, off, 64); a1 += __shfl_xor(a1, off, 64);
        a2 += __shfl_xor(a2, off, 64); a3 += __shfl_xor(a3, off, 64);
        a4 += __shfl_xor(a4, off, 64); a5 += __shfl_xor(a5, off, 64);
        a6 += __shfl_xor(a6, off, 64); a7 += __shfl_xor(a7, off, 64);
    }
    if (sub == 0) {
        unsigned int* dst = (unsigned int*)(Lm + (size_t)wid * D + 8 * sl);
        *(uint4*)dst = make_uint4(pack_bf16(a0, a1), pack_bf16(a2, a3),
                                  pack_bf16(a4, a5), pack_bf16(a6, a7));
    }
}

// ---------------- fused layer via MFMA: Y = leaky([Lm+E | Lm*E] @ [W1;W2] + b1+b2)
// un-normalized Y -> Ebf (bf16) + E5 (e5m2); row-normalized Y -> all_e.
#define AP 136  // A/B^T row stride in shorts (128 + 8 pad -> 4-bank stagger)
__global__ __launch_bounds__(256) void layer_fused_mfma(const unsigned short* __restrict__ Lm,
                                                        unsigned short* __restrict__ Ebf,
                                                        unsigned char* __restrict__ E5,
                                                        const float* __restrict__ W1,
                                                        const float* __restrict__ b1,
                                                        const float* __restrict__ W2,
                                                        const float* __restrict__ b2,
                                                        float* __restrict__ all_e, int layer) {
    __shared__ unsigned short sBt[64 * AP];    // B^T[n][k] bf16 (k<64: W1, k>=64: W2)
    __shared__ float sBias[64];
    __shared__ unsigned short sA[4][16 * AP];  // per-wave A staging

    int t = threadIdx.x;
    for (int i = t; i < 4096; i += 256) {
        int k = i >> 6, n = i & 63;
        sBt[n * AP + k] = f32_to_bf16(W1[i]);
        sBt[n * AP + 64 + k] = f32_to_bf16(W2[i]);
    }
    if (t < 64) sBias[t] = b1[t] + b2[t];
    __syncthreads();

    int w = t >> 6, lane = t & 63;
    int quad = lane >> 4, l16 = lane & 15;

    short8 bfrag[4][4];
#pragma unroll
    for (int ks = 0; ks < 4; ks++)
#pragma unroll
        for (int ct = 0; ct < 4; ct++)
            bfrag[ks][ct] = *(const short8*)&sBt[(ct * 16 + l16) * AP + ks * 32 + quad * 8];

    float bias[4];
#pragma unroll
    for (int ct = 0; ct < 4; ct++) bias[ct] = sBias[ct * 16 + l16];

    unsigned short* A = sA[w];
    int col_off = (layer + 1) * 64;
    int nwaves = gridDim.x * 4;

    for (int tile = blockIdx.x * 4 + w; tile < N_CNT / 16; tile += nwaves) {
        int rbase = tile * 16;
#pragma unroll
        for (int p = 0; p < 4; p++) {
            int r = p * 4 + quad;
            int c = l16 * 4;
            uint2 lw = *(const uint2*)(Lm + (size_t)(rbase + r) * 64 + c);
            float l0 = bf16_lo(lw.x), l1 = bf16_hi(lw.x);
            float l2 = bf16_lo(lw.y), l3 = bf16_hi(lw.y);
            ushort4 eh = *(const ushort4*)(Ebf + (size_t)(rbase + r) * 64 + c);
            float e0 = bf16_to_f32(eh.x), e1 = bf16_to_f32(eh.y);
            float e2 = bf16_to_f32(eh.z), e3 = bf16_to_f32(eh.w);
            *(uint2*)&A[r * AP + c] = make_uint2(pack_bf16(l0 + e0, l1 + e1),
                                                pack_bf16(l2 + e2, l3 + e3));
            *(uint2*)&A[r * AP + 64 + c] = make_uint2(pack_bf16(l0 * e0, l1 * e1),
                                                      pack_bf16(l2 * e2, l3 * e3));
        }
        floatx4 acc[4];
#pragma unroll
        for (int ct = 0; ct < 4; ct++) {
            acc[ct][0] = bias[ct]; acc[ct][1] = bias[ct];
            acc[ct][2] = bias[ct]; acc[ct][3] = bias[ct];
        }
#pragma unroll
        for (int ks = 0; ks < 4; ks++) {
            short8 af = *(const short8*)&A[l16 * AP + ks * 32 + quad * 8];
#pragma unroll
            for (int ct = 0; ct < 4; ct++)
                acc[ct] = __builtin_amdgcn_mfma_f32_16x16x32_bf16(af, bfrag[ks][ct], acc[ct], 0, 0, 0);
        }
        float y[4][4];
        float ssq[4] = {0.f, 0.f, 0.f, 0.f};
#pragma unroll
        for (int ct = 0; ct < 4; ct++)
#pragma unroll
            for (int reg = 0; reg < 4; reg++) {
                float v = acc[ct][reg];
                v = (v > 0.f) ? v : 0.2f * v;
                y[ct][reg] = v;
                ssq[reg] += v * v;
            }
#pragma unroll
        for (int reg = 0; reg < 4; reg++) {
            float ss = ssq[reg];
            ss += __shfl_xor(ss, 1, 64);
            ss += __shfl_xor(ss, 2, 64);
            ss += __shfl_xor(ss, 4, 64);
            ss += __shfl_xor(ss, 8, 64);
            ssq[reg] = fmaxf(sqrtf(ss), EPS_F);
        }
#pragma unroll
        for (int reg = 0; reg < 4; reg++) {
            int row = rbase + quad * 4 + reg;
            float inv = 1.0f / ssq[reg];
#pragma unroll
            for (int ct = 0; ct < 4; ct++) {
                int col = ct * 16 + l16;
                float v = y[ct][reg];
                Ebf[(size_t)row * 64 + col] = f32_to_bf16(v);
                E5[(size_t)row * 64 + col] = f32_to_e5(v);
                all_e[(size_t)row * 256 + col_off + col] = v * inv;
            }
        }
    }
}

// ---------------- scoring: one wave per sample, per-sample partials (NO atomics)
__device__ __forceinline__ float dot4(float4 a, float4 b) {
    return a.x * b.x + a.y * b.y + a.z * b.z + a.w * b.w;
}

__global__ __launch_bounds__(256) void score_kernel(const float* __restrict__ all_e,
                                                    const int* __restrict__ users,
                                                    const int* __restrict__ pos,
                                                    const int* __restrict__ neg,
                                                    float4* __restrict__ partials) {
    int wid = (blockIdx.x * blockDim.x + threadIdx.x) >> 6;
    int lane = threadIdx.x & 63;
    if (wid >= BATCH) return;
    int ui = users[wid];
    int pi = pos[wid];
    int ni = neg[wid];
    const float4* uv4 = (const float4*)(all_e + (size_t)ui * 256);
    const float4* pv4 = (const float4*)(all_e + (size_t)pi * 256);
    const float4* nv4 = (const float4*)(all_e + (size_t)ni * 256);
    float4 uv = uv4[lane];
    float4 pv = pv4[lane];
    float4 nv = nv4[lane];
    float s_up = dot4(uv, pv);
    float s_un = dot4(uv, nv);
    float s_uu = dot4(uv, uv);
    float s_pp = dot4(pv, pv);
    float s_nn = dot4(nv, nv);
#pragma unroll
    for (int off = 32; off >= 1; off >>= 1) {
        s_up += __shfl_xor(s_up, off, 64);
        s_un += __shfl_xor(s_un, off, 64);
        s_uu += __shfl_xor(s_uu, off, 64);
        s_pp += __shfl_xor(s_pp, off, 64);
        s_nn += __shfl_xor(s_nn, off, 64);
    }
    if (lane == 0) {
        float x = s_up - s_un;
        float ls = fminf(x, 0.f) - log1pf(expf(-fabsf(x)));  // log_sigmoid
        partials[wid] = make_float4(-ls, s_uu, s_pp, s_nn);
    }
}

// single-block tree reduction over 4096 float4 partials + final scalar
__global__ __launch_bounds__(256) void reduce_finalize(const float4* __restrict__ partials,
                                                       float* __restrict__ out) {
    __shared__ float4 s[256];
    int t = threadIdx.x;
    float4 a = make_float4(0.f, 0.f, 0.f, 0.f);
    for (int i = t; i < BATCH; i += 256) {
        float4 p = partials[i];
        a.x += p.x; a.y += p.y; a.z += p.z; a.w += p.w;
    }
    s[t] = a;
    __syncthreads();
    for (int off = 128; off >= 1; off >>= 1) {
        if (t < off) {
            s[t].x += s[t + off].x;
            s[t].y += s[t + off].y;
            s[t].z += s[t + off].z;
            s[t].w += s[t + off].w;
        }
        __syncthreads();
    }
    if (t == 0) {
        float bpr = s[0].x / (float)BATCH;
        float l2norm = (s[0].y + s[0].z + sqrtf(s[0].w)) * 0.5f;
        out[0] = bpr + L2_REG_F * l2norm / (float)BATCH;
    }
}

extern "C" void kernel_launch(void* const* d_in, const int* in_sizes, int n_in,
                              void* d_out, int out_size, void* d_ws, size_t ws_size,
                              hipStream_t stream) {
    const int* users = (const int*)d_in[0];
    const int* pos_items = (const int*)d_in[1];
    const int* neg_items = (const int*)d_in[2];
    const int* rows = (const int*)d_in[3];
    const int* cols = (const int*)d_in[4];
    const float* vals = (const float*)d_in[5];
    const float* user_embed = (const float*)d_in[6];
    const float* item_embed = (const float*)d_in[7];
    const float* W1 = (const float*)d_in[8];
    const float* b1 = (const float*)d_in[9];
    const float* W2 = (const float*)d_in[10];
    const float* b2 = (const float*)d_in[11];
    float* out = (float*)d_out;

    char* ws = (char*)d_ws;
    // workspace layout: ~160.9 MB (r1 passed at ~180 MB; r9's crash was the fp8
    // builtins, not size — e5m2 path uses only fp16 cvt)
    size_t off_alle = 0;                                     // 102,400,000
    size_t off_packed = off_alle + (size_t)N_CNT * 256 * 4;  // 25,600,000
    size_t off_Ebf = off_packed + (size_t)NNZ_CNT * 8;       // 12,800,000
    size_t off_Lm = off_Ebf + (size_t)N_CNT * D * 2;         // 12,800,000 (bf16)
    size_t off_E5 = off_Lm + (size_t)N_CNT * D * 2;          // 6,400,000 (e5m2)
    size_t off_rowptr = off_E5 + (size_t)N_CNT * D;          // 400,128
    size_t off_blkB = off_rowptr + 400128;                   // 2,048
    size_t off_bcnt = off_blkB + 2048;                       // 400,384
    size_t off_part = off_bcnt + 400384;                     // 65,536

    float* all_e = (float*)(ws + off_alle);
    float2* bbuf = (float2*)(ws + off_alle);   // aliases all_e; dead before init_E runs
    float2* packed = (float2*)(ws + off_packed);
    unsigned short* Ebf = (unsigned short*)(ws + off_Ebf);
    unsigned short* Lm = (unsigned short*)(ws + off_Lm);
    unsigned char* E5 = (unsigned char*)(ws + off_E5);
    int* row_ptr = (int*)(ws + off_rowptr);
    int* blkB = (int*)(ws + off_blkB);
    int* bcnt = (int*)(ws + off_bcnt);
    float4* partials = (float4*)(ws + off_part);

    // bucketed multisplit with exclusive per-(bucket,block) regions
    bucket_hist<<<SC_NBLK, 1024, 0, stream>>>(rows, bcnt);
    scan_p1<<<BCNT_NBLK, 256, 0, stream>>>(bcnt, blkB, BCNT_N);
    scan_p2<<<1, 512, 0, stream>>>(blkB, BCNT_NBLK);
    scan_p3<<<BCNT_NBLK, 256, 0, stream>>>(bcnt, blkB, bcnt, BCNT_N);  // in-place
    block_scatter<<<SC_NBLK, 1024, 0, stream>>>(rows, cols, vals, bcnt, bbuf);
    csr_finalize<<<NBUCKET, 1024, 0, stream>>>(bbuf, bcnt, row_ptr, packed);

    // embeddings (after csr_finalize: bbuf aliases all_e)
    init_E<<<(N_CNT * D) / 256, 256, 0, stream>>>(user_embed, item_embed, Ebf, E5, all_e);

    for (int l = 0; l < LAYERS; l++) {
        spmm_e5<<<(N_CNT * 64) / 256, 256, 0, stream>>>(packed, row_ptr, E5, Lm);
        layer_fused_mfma<<<784, 256, 0, stream>>>(Lm, Ebf, E5, W1 + (size_t)l * 4096,
                                                  b1 + (size_t)l * 64, W2 + (size_t)l * 4096,
                                                  b2 + (size_t)l * 64, all_e, l);
    }

    score_kernel<<<(BATCH * 64) / 256, 256, 0, stream>>>(all_e, users, pos_items, neg_items,
                                                         partials);
    reduce_finalize<<<1, 256, 0, stream>>>(partials, out);
}